// Round 7
// baseline (232.158 us; speedup 1.0000x reference)
//
#include <hip/hip_runtime.h>

typedef unsigned short u16;
typedef __bf16 bf16x8 __attribute__((ext_vector_type(8)));
typedef float f32x4 __attribute__((ext_vector_type(4)));

struct alignas(16) V4 { unsigned x, y, z, w; };

// f32 -> bf16 RTNE (bit-twiddle; HW-verified R1/R4)
__device__ __forceinline__ u16 f2b(float f) {
  unsigned u = __builtin_bit_cast(unsigned, f);
  u += 0x7FFFu + ((u >> 16) & 1u);
  return (u16)(u >> 16);
}
// RTNE pack of two f32 -> u32 (lo = a, hi = b)
__device__ __forceinline__ unsigned pk2(float a, float b) {
  return (unsigned)f2b(a) | ((unsigned)f2b(b) << 16);
}
__device__ __forceinline__ bf16x8 asb(V4 v) { return __builtin_bit_cast(bf16x8, v); }
__device__ __forceinline__ bf16x8 mk8(unsigned a, unsigned b, unsigned c, unsigned d) {
  V4 v; v.x = a; v.y = b; v.z = c; v.w = d; return asb(v);
}
__device__ __forceinline__ V4 ldg16(const u16* p) { return *reinterpret_cast<const V4*>(p); }
__device__ __forceinline__ f32x4 mfma16(bf16x8 a, bf16x8 b, f32x4 c) {
  return __builtin_amdgcn_mfma_f32_16x16x32_bf16(a, b, c, 0, 0, 0);
}

// ---------------------------------------------------------------------------
// Prep: transpose+cast weights to bf16, cast descriptor to bf16.
// ---------------------------------------------------------------------------
__global__ __launch_bounds__(256) void k_prep(
    const float* __restrict__ wq, const float* __restrict__ wk,
    const float* __restrict__ wv, const float* __restrict__ wd,
    const float* __restrict__ wo, const float* __restrict__ desc,
    u16* __restrict__ wqT, u16* __restrict__ wkT, u16* __restrict__ wvT,
    u16* __restrict__ wdT, u16* __restrict__ woT, u16* __restrict__ descb) {
  int i = blockIdx.x * 256 + threadIdx.x;
  if (i < 32768) {                                   // wqT[n][d] = wq[d][n]
    int n = i >> 6, d = i & 63;
    wqT[i] = f2b(wq[d * 512 + n]);
  } else if (i < 65536) {
    int j = i - 32768; int n = j >> 6, d = j & 63;
    wkT[j] = f2b(wk[d * 512 + n]);
  } else if (i < 98304) {
    int j = i - 65536; int n = j >> 6, d = j & 63;
    wvT[j] = f2b(wv[d * 512 + n]);
  } else if (i < 114688) {                           // wdT[e][v] = wd[v][e]
    int j = i - 98304; int e = j >> 8, v = j & 255;
    wdT[j] = f2b(wd[v * 64 + e]);
  } else if (i < 147456) {                           // woT[n][k] = wo[k][n]
    int j = i - 114688; int n = j >> 9, kk = j & 511;
    woT[j] = f2b(wo[kk * 64 + n]);
  } else if (i < 409600) {                           // descb, 4 elems/thread
    int j = (i - 147456) * 4;
    const f32x4 dv = *reinterpret_cast<const f32x4*>(desc + j);
    uint2 pw; pw.x = pk2(dv[0], dv[1]); pw.y = pk2(dv[2], dv[3]);
    *reinterpret_cast<uint2*>(descb + j) = pw;
  }
}

// ---------------------------------------------------------------------------
// Conv3d(P=4,stride=4) + LayerNorm + pos_emb -> vox_emb bf16 [16384][64]
// ---------------------------------------------------------------------------
__global__ __launch_bounds__(256) void k_convln(
    const float* __restrict__ vox, const float* __restrict__ cw,
    const float* __restrict__ cb, const float* __restrict__ lng,
    const float* __restrict__ lnb, const float* __restrict__ pos,
    u16* __restrict__ vox_emb) {
  __shared__ float wT[64 * 65];
  __shared__ float pl[4][64];
  const int t = threadIdx.x;
  for (int i = t; i < 4096; i += 256) wT[(i & 63) * 65 + (i >> 6)] = cw[i];
  const int w = t >> 6, lane = t & 63;
  const float cbl = cb[lane], lg = lng[lane], lb = lnb[lane];
  const int i3 = lane >> 4, j3 = (lane >> 2) & 3, k3 = lane & 3;
  for (int i = 0; i < 8; ++i) {
    const int row = blockIdx.x * 32 + w * 8 + i;
    const int b = row >> 12, np = row & 4095;
    const int pd = np >> 8, ph = (np >> 4) & 15, pw = np & 15;
    __syncthreads();
    pl[w][lane] = vox[(size_t)b * 262144 + (size_t)(pd * 4 + i3) * 4096 +
                      (ph * 4 + j3) * 64 + (pw * 4 + k3)];
    __syncthreads();
    float acc = cbl;
    #pragma unroll
    for (int v = 0; v < 64; ++v) acc += pl[w][v] * wT[v * 65 + lane];
    float s1 = acc, s2 = acc * acc;
    #pragma unroll
    for (int m = 1; m < 64; m <<= 1) { s1 += __shfl_xor(s1, m); s2 += __shfl_xor(s2, m); }
    const float mu = s1 * (1.0f / 64.0f);
    const float var = s2 * (1.0f / 64.0f) - mu * mu;
    const float y = (acc - mu) * rsqrtf(var + 1e-5f) * lg + lb + pos[np * 64 + lane];
    vox_emb[(size_t)row * 64 + lane] = f2b(y);
  }
}

// ---------------------------------------------------------------------------
// des_emb = descb[4096][256] @ wd + bd -> bf16 [4096][64]
// ---------------------------------------------------------------------------
__global__ __launch_bounds__(64) void k_des(
    const u16* __restrict__ descb, const u16* __restrict__ wdT,
    const float* __restrict__ bd, u16* __restrict__ desemb) {
  const int lane = threadIdx.x, lr = lane & 15, lc = lane >> 4;
  const int sd0 = blockIdx.x * 16;
  bf16x8 db[8];
  #pragma unroll
  for (int kc = 0; kc < 8; ++kc)
    db[kc] = asb(ldg16(descb + (size_t)(sd0 + lr) * 256 + kc * 32 + lc * 8));
  #pragma unroll
  for (int et = 0; et < 4; ++et) {
    f32x4 acc = {0.f, 0.f, 0.f, 0.f};
    #pragma unroll
    for (int kc = 0; kc < 8; ++kc) {
      const bf16x8 wa = asb(ldg16(wdT + (size_t)(et * 16 + lr) * 256 + kc * 32 + lc * 8));
      acc = mfma16(wa, db[kc], acc);
    }
    const f32x4 bdv = *reinterpret_cast<const f32x4*>(bd + et * 16 + lc * 4);
    uint2 pw;
    pw.x = pk2(acc[0] + bdv[0], acc[1] + bdv[1]);
    pw.y = pk2(acc[2] + bdv[2], acc[3] + bdv[3]);
    *reinterpret_cast<uint2*>(desemb + (size_t)(sd0 + lr) * 64 + et * 16 + lc * 4) = pw;
  }
}

// ---------------------------------------------------------------------------
// K/V projections. Both outputs stored in MFMA-fragment-interleaved order so
// k_attn fragments are single 16B loads (same values, permuted addresses).
// ek = exp(-|k|^2) f32.
// ---------------------------------------------------------------------------
__global__ __launch_bounds__(64) void k_kvproj(
    const u16* __restrict__ desemb, const u16* __restrict__ wkT,
    const float* __restrict__ bk, const u16* __restrict__ wvT,
    const float* __restrict__ bv, u16* __restrict__ kb,
    float* __restrict__ ek, u16* __restrict__ vtb) {
  const int lane = threadIdx.x, lr = lane & 15, lc = lane >> 4;
  const int x = blockIdx.x, half = blockIdx.y;
  const int b = x >> 6, sd0 = (x & 63) * 16;
  const u16* drow = desemb + (size_t)(x * 16 + lr) * 64;
  const bf16x8 da0 = asb(ldg16(drow + lc * 8));
  const bf16x8 da1 = asb(ldg16(drow + 32 + lc * 8));
  float sq = 0.f;
  #pragma unroll
  for (int et = 0; et < 16; ++et) {                 // K pass (flipped)
    const int etg = half * 16 + et;
    const u16* wrow = wkT + (size_t)(etg * 16 + lr) * 64;
    f32x4 acc = {0.f, 0.f, 0.f, 0.f};
    acc = mfma16(asb(ldg16(wrow + lc * 8)), da0, acc);
    acc = mfma16(asb(ldg16(wrow + 32 + lc * 8)), da1, acc);
    const f32x4 bkv = *reinterpret_cast<const f32x4*>(bk + etg * 16 + lc * 4);
    const float k0 = acc[0] + bkv[0], k1 = acc[1] + bkv[1];
    const float k2 = acc[2] + bkv[2], k3 = acc[3] + bkv[3];
    sq += k0 * k0 + k1 * k1 + k2 * k2 + k3 * k3;
    const int h = etg >> 2, ein = etg & 3;
    const int koff = (ein >> 1) * 32 + lc * 8 + (ein & 1) * 4;
    uint2 pw; pw.x = pk2(k0, k1); pw.y = pk2(k2, k3);
    *reinterpret_cast<uint2*>(kb + ((size_t)(b * 8 + h) * 1024 + sd0 + lr) * 64 + koff) = pw;
    if ((etg & 3) == 3) {
      float s = sq;
      s += __shfl_xor(s, 16); s += __shfl_xor(s, 32);
      if (lc == 0) ek[(size_t)(b * 8 + h) * 1024 + sd0 + lr] = __expf(-s);
      sq = 0.f;
    }
  }
  #pragma unroll
  for (int et = 0; et < 16; ++et) {                 // V pass
    const int etg = half * 16 + et;
    const u16* wrow = wvT + (size_t)(etg * 16 + lr) * 64;
    f32x4 acc = {0.f, 0.f, 0.f, 0.f};
    acc = mfma16(da0, asb(ldg16(wrow + lc * 8)), acc);
    acc = mfma16(da1, asb(ldg16(wrow + 32 + lc * 8)), acc);
    const float bvs = bv[etg * 16 + lr];
    const int h = etg >> 2;
    const int voff = ((x & 63) >> 1) * 32 + lc * 8 + (x & 1) * 4;
    uint2 pw;
    pw.x = pk2(acc[0] + bvs, acc[1] + bvs);
    pw.y = pk2(acc[2] + bvs, acc[3] + bvs);
    *reinterpret_cast<uint2*>(vtb + ((size_t)(b * 8 + h) * 64 + (etg & 3) * 16 + lr) * 1024 +
                              voff) = pw;
  }
}

// ---------------------------------------------------------------------------
// Fused Q-projection + L2 attention. R4-exact arithmetic (frozen).
// R7: no-LDS + explicit 1-deep register prefetch of K fragments and ek
// vectors (compiler refused to pipeline in R6 -> latency-bound). V fragments
// issued at iteration top, consumed after QK+exp (~300cyc of cover).
// Prefetch at kk=31 reads <=4KB past the per-bh region — still inside ws
// (kb -> vtb -> ek -> attn contiguous), values unused.
// ---------------------------------------------------------------------------
__global__ __launch_bounds__(256, 4) void k_attn(
    const u16* __restrict__ vox_emb, const u16* __restrict__ wqT,
    const float* __restrict__ bq, const float* __restrict__ alpha,
    const u16* __restrict__ kb, const float* __restrict__ ekg,
    const u16* __restrict__ vtb, u16* __restrict__ attn) {
  const int t = threadIdx.x, w = t >> 6, lane = t & 63, lr = lane & 15, lc = lane >> 4;
  const int bh = blockIdx.y, b = bh >> 3, h = bh & 7;
  const int q0 = blockIdx.x * 128 + w * 32;   // this wave's 32 q rows

  // ---- Q: q = vox_emb @ wq + bq; fragments hold f2b(q) (unscaled, R4-exact)
  bf16x8 qf0[2], qf1[2];
  float av[2];
  {
    bf16x8 vb0[2], vb1[2];
    #pragma unroll
    for (int g = 0; g < 2; ++g) {
      const u16* vrow = vox_emb + (size_t)(b * 4096 + q0 + g * 16 + lr) * 64;
      vb0[g] = asb(ldg16(vrow + lc * 8));
      vb1[g] = asb(ldg16(vrow + 32 + lc * 8));
    }
    float sq[2] = {0.f, 0.f};
    unsigned qd[2][4][2];
    #pragma unroll
    for (int et = 0; et < 4; ++et) {
      const u16* wrow = wqT + (size_t)((h * 4 + et) * 16 + lr) * 64;
      const bf16x8 wa0 = asb(ldg16(wrow + lc * 8));
      const bf16x8 wa1 = asb(ldg16(wrow + 32 + lc * 8));
      const f32x4 bqv = *reinterpret_cast<const f32x4*>(bq + (h * 4 + et) * 16 + lc * 4);
      #pragma unroll
      for (int g = 0; g < 2; ++g) {
        f32x4 acc = {0.f, 0.f, 0.f, 0.f};
        acc = mfma16(wa0, vb0[g], acc);
        acc = mfma16(wa1, vb1[g], acc);
        const float v0 = acc[0] + bqv[0], v1 = acc[1] + bqv[1];
        const float v2 = acc[2] + bqv[2], v3 = acc[3] + bqv[3];
        sq[g] += v0 * v0 + v1 * v1 + v2 * v2 + v3 * v3;
        qd[g][et][0] = pk2(v0, v1);
        qd[g][et][1] = pk2(v2, v3);
      }
    }
    const float ca = 0.125f * alpha[0];
    #pragma unroll
    for (int g = 0; g < 2; ++g) {
      float s = sq[g];
      s += __shfl_xor(s, 16); s += __shfl_xor(s, 32);
      av[g] = ca * __expf(-s);      // alpha*SCALE*exp(-|q|^2), fp32 q
      qf0[g] = mk8(qd[g][0][0], qd[g][0][1], qd[g][1][0], qd[g][1][1]);
      qf1[g] = mk8(qd[g][2][0], qd[g][2][1], qd[g][3][0], qd[g][3][1]);
    }
  }

  const f32x4 z = {0.f, 0.f, 0.f, 0.f};
  f32x4 o[2][4];
  float dn[2] = {0.f, 0.f};
  #pragma unroll
  for (int g = 0; g < 2; ++g)
    #pragma unroll
    for (int m = 0; m < 4; ++m) o[g][m] = z;

  const V4* kp = reinterpret_cast<const V4*>(kb) + (size_t)bh * 1024 * 8 +
                 (size_t)lr * 8 + lc;
  const char* vp = reinterpret_cast<const char*>(vtb) + (size_t)bh * 64 * 2048 +
                   (size_t)lr * 2048 + lc * 16;
  const float* ep = ekg + (size_t)bh * 1024 + lc * 4;

  // prologue: load kk=0's K fragments + ek
  V4 ck00 = kp[0], ck01 = kp[4], ck10 = kp[128], ck11 = kp[132];
  f32x4 ce0 = *reinterpret_cast<const f32x4*>(ep);
  f32x4 ce1 = *reinterpret_cast<const f32x4*>(ep + 16);

  #pragma unroll 2
  for (int kk = 0; kk < 32; ++kk) {
    // ---- prefetch next iteration's K + ek (critical path at iter start)
    const V4* kpn = kp + 256;
    const float* epn = ep + 32;
    V4 nk00 = kpn[0], nk01 = kpn[4], nk10 = kpn[128], nk11 = kpn[132];
    f32x4 ne0 = *reinterpret_cast<const f32x4*>(epn);
    f32x4 ne1 = *reinterpret_cast<const f32x4*>(epn + 16);
    // ---- V fragments for current iteration (consumed after QK+exp chain)
    const bf16x8 va0 = asb(*reinterpret_cast<const V4*>(vp));
    const bf16x8 va1 = asb(*reinterpret_cast<const V4*>(vp + 16 * 2048));
    const bf16x8 va2 = asb(*reinterpret_cast<const V4*>(vp + 32 * 2048));
    const bf16x8 va3 = asb(*reinterpret_cast<const V4*>(vp + 48 * 2048));

    const bf16x8 ka00 = asb(ck00), ka01 = asb(ck01);
    const bf16x8 ka10 = asb(ck10), ka11 = asb(ck11);
    #pragma unroll
    for (int g = 0; g < 2; ++g) {
      f32x4 s0 = z, s1 = z;
      s0 = mfma16(ka00, qf0[g], s0); s0 = mfma16(ka01, qf1[g], s0);
      s1 = mfma16(ka10, qf0[g], s1); s1 = mfma16(ka11, qf1[g], s1);
      // R4-exact: p = expf(aeq * ek * expf(2*q.k))
      const float p00 = __expf(av[g] * ce0[0] * __expf(2.0f * s0[0]));
      const float p01 = __expf(av[g] * ce0[1] * __expf(2.0f * s0[1]));
      const float p02 = __expf(av[g] * ce0[2] * __expf(2.0f * s0[2]));
      const float p03 = __expf(av[g] * ce0[3] * __expf(2.0f * s0[3]));
      const float p10 = __expf(av[g] * ce1[0] * __expf(2.0f * s1[0]));
      const float p11 = __expf(av[g] * ce1[1] * __expf(2.0f * s1[1]));
      const float p12 = __expf(av[g] * ce1[2] * __expf(2.0f * s1[2]));
      const float p13 = __expf(av[g] * ce1[3] * __expf(2.0f * s1[3]));
      dn[g] += ((p00 + p01) + (p02 + p03)) + ((p10 + p11) + (p12 + p13));
      const bf16x8 pf = mk8(pk2(p00, p01), pk2(p02, p03),
                            pk2(p10, p11), pk2(p12, p13));
      o[g][0] = mfma16(va0, pf, o[g][0]);
      o[g][1] = mfma16(va1, pf, o[g][1]);
      o[g][2] = mfma16(va2, pf, o[g][2]);
      o[g][3] = mfma16(va3, pf, o[g][3]);
    }
    // ---- rotate
    kp = kpn; ep = epn; vp += 64;
    ck00 = nk00; ck01 = nk01; ck10 = nk10; ck11 = nk11;
    ce0 = ne0; ce1 = ne1;
  }

  u16* obase = attn + (size_t)(b * 4096 + q0 + lr) * 512 + h * 64 + lc * 4;
  #pragma unroll
  for (int g = 0; g < 2; ++g) {
    float s = dn[g];
    s += __shfl_xor(s, 16); s += __shfl_xor(s, 32);   // sum lane's k-subsets over lc
    const float inv = 1.0f / s;
    #pragma unroll
    for (int m = 0; m < 4; ++m) {
      uint2 pw;
      pw.x = pk2(o[g][m][0] * inv, o[g][m][1] * inv);
      pw.y = pk2(o[g][m][2] * inv, o[g][m][3] * inv);
      *reinterpret_cast<uint2*>(obase + (size_t)g * 16 * 512 + m * 16) = pw;
    }
  }
}

// ---------------------------------------------------------------------------
// out = attn[16384][512] @ wo + bo -> fp32 [16384][64]
// ---------------------------------------------------------------------------
__global__ __launch_bounds__(64) void k_out(
    const u16* __restrict__ attn, const u16* __restrict__ woT,
    const float* __restrict__ bo, float* __restrict__ out) {
  const int lane = threadIdx.x, lr = lane & 15, lc = lane >> 4;
  const int np0 = blockIdx.x * 16;
  const u16* arow = attn + (size_t)(np0 + lr) * 512;
  f32x4 acc[4] = {{0.f,0.f,0.f,0.f},{0.f,0.f,0.f,0.f},{0.f,0.f,0.f,0.f},{0.f,0.f,0.f,0.f}};
  #pragma unroll
  for (int kc = 0; kc < 16; ++kc) {
    const bf16x8 bfr = asb(ldg16(arow + kc * 32 + lc * 8));
    #pragma unroll
    for (int et = 0; et < 4; ++et) {
      const bf16x8 wa = asb(ldg16(woT + (size_t)(et * 16 + lr) * 512 + kc * 32 + lc * 8));
      acc[et] = mfma16(wa, bfr, acc[et]);
    }
  }
  #pragma unroll
  for (int et = 0; et < 4; ++et) {
    const f32x4 bov = *reinterpret_cast<const f32x4*>(bo + et * 16 + lc * 4);
    const f32x4 r = acc[et] + bov;
    *reinterpret_cast<f32x4*>(out + (size_t)(np0 + lr) * 64 + et * 16 + lc * 4) = r;
  }
}

// ---------------------------------------------------------------------------
extern "C" void kernel_launch(void* const* d_in, const int* in_sizes, int n_in,
                              void* d_out, int out_size, void* d_ws, size_t ws_size,
                              hipStream_t stream) {
  (void)in_sizes; (void)n_in; (void)out_size; (void)ws_size;
  const float* vox   = (const float*)d_in[0];
  const float* desc  = (const float*)d_in[1];
  const float* cw    = (const float*)d_in[2];
  const float* cb    = (const float*)d_in[3];
  const float* lng   = (const float*)d_in[4];
  const float* lnb   = (const float*)d_in[5];
  const float* pos   = (const float*)d_in[6];
  const float* wq    = (const float*)d_in[7];
  const float* bq    = (const float*)d_in[8];
  const float* wk    = (const float*)d_in[9];
  const float* bk    = (const float*)d_in[10];
  const float* wv    = (const float*)d_in[11];
  const float* bv    = (const float*)d_in[12];
  const float* wd    = (const float*)d_in[13];
  const float* bd    = (const float*)d_in[14];
  const float* alpha = (const float*)d_in[15];
  const float* wo    = (const float*)d_in[16];
  const float* bo    = (const float*)d_in[17];
  float* out = (float*)d_out;

  char* ws = (char*)d_ws;
  size_t off = 0;
  auto alloc = [&](size_t bytes) {
    char* p = ws + off;
    off += (bytes + 255) & ~(size_t)255;
    return p;
  };
  u16*   vox_emb = (u16*)alloc((size_t)16384 * 64 * 2);
  u16*   descb   = (u16*)alloc((size_t)4096 * 256 * 2);
  u16*   desemb  = (u16*)alloc((size_t)4096 * 64 * 2);
  u16*   kb      = (u16*)alloc((size_t)4096 * 512 * 2);
  u16*   vtb     = (u16*)alloc((size_t)4096 * 512 * 2);
  float* ek      = (float*)alloc((size_t)32768 * 4);
  u16*   attn    = (u16*)alloc((size_t)16384 * 512 * 2);
  u16*   wqT     = (u16*)alloc((size_t)32768 * 2);
  u16*   wkT     = (u16*)alloc((size_t)32768 * 2);
  u16*   wvT     = (u16*)alloc((size_t)32768 * 2);
  u16*   wdT     = (u16*)alloc((size_t)16384 * 2);
  u16*   woT     = (u16*)alloc((size_t)32768 * 2);

  k_prep<<<1600, 256, 0, stream>>>(wq, wk, wv, wd, wo, desc, wqT, wkT, wvT, wdT, woT, descb);
  k_convln<<<512, 256, 0, stream>>>(vox, cw, cb, lng, lnb, pos, vox_emb);
  k_des<<<256, 64, 0, stream>>>(descb, wdT, bd, desemb);
  k_kvproj<<<dim3(256, 2), 64, 0, stream>>>(desemb, wkT, bk, wvT, bv, kb, ek, vtb);
  k_attn<<<dim3(32, 32), 256, 0, stream>>>(vox_emb, wqT, bq, alpha, kb, ek, vtb, attn);
  k_out<<<1024, 64, 0, stream>>>(attn, woT, bo, out);
}

// Round 8
// 192.344 us; speedup vs baseline: 1.2070x; 1.2070x over previous
//
#include <hip/hip_runtime.h>

typedef unsigned short u16;
typedef __bf16 bf16x8 __attribute__((ext_vector_type(8)));
typedef float f32x4 __attribute__((ext_vector_type(4)));

struct alignas(16) V4 { unsigned x, y, z, w; };

#if __has_builtin(__builtin_amdgcn_exp2f)
#define EXP2(x) __builtin_amdgcn_exp2f(x)
#else
#define EXP2(x) __expf((x) * 0.6931471805599453f)
#endif
#define L2E 1.4426950408889634f

// f32 -> bf16 RTNE (bit-twiddle; HW-verified R1/R4)
__device__ __forceinline__ u16 f2b(float f) {
  unsigned u = __builtin_bit_cast(unsigned, f);
  u += 0x7FFFu + ((u >> 16) & 1u);
  return (u16)(u >> 16);
}
// RTNE pack of two f32 -> u32 (lo = a, hi = b)
__device__ __forceinline__ unsigned pk2(float a, float b) {
  return (unsigned)f2b(a) | ((unsigned)f2b(b) << 16);
}
// HW packed cvt: used ONLY for P fragment (softmax self-normalizing; R3
// exonerated semantics, worst-case bias ~2e-6 on output)
__device__ __forceinline__ unsigned pkbf(float a, float b) {
  unsigned d;
  asm("v_cvt_pk_bf16_f32 %0, %1, %2" : "=v"(d) : "v"(a), "v"(b));
  return d;
}
__device__ __forceinline__ bf16x8 asb(V4 v) { return __builtin_bit_cast(bf16x8, v); }
__device__ __forceinline__ bf16x8 mk8(unsigned a, unsigned b, unsigned c, unsigned d) {
  V4 v; v.x = a; v.y = b; v.z = c; v.w = d; return asb(v);
}
__device__ __forceinline__ V4 ldg16(const u16* p) { return *reinterpret_cast<const V4*>(p); }
__device__ __forceinline__ f32x4 mfma16(bf16x8 a, bf16x8 b, f32x4 c) {
  return __builtin_amdgcn_mfma_f32_16x16x32_bf16(a, b, c, 0, 0, 0);
}

// ---------------------------------------------------------------------------
// Prep: transpose+cast weights to bf16, cast descriptor to bf16.
// ---------------------------------------------------------------------------
__global__ __launch_bounds__(256) void k_prep(
    const float* __restrict__ wq, const float* __restrict__ wk,
    const float* __restrict__ wv, const float* __restrict__ wd,
    const float* __restrict__ wo, const float* __restrict__ desc,
    u16* __restrict__ wqT, u16* __restrict__ wkT, u16* __restrict__ wvT,
    u16* __restrict__ wdT, u16* __restrict__ woT, u16* __restrict__ descb) {
  int i = blockIdx.x * 256 + threadIdx.x;
  if (i < 32768) {                                   // wqT[n][d] = wq[d][n]
    int n = i >> 6, d = i & 63;
    wqT[i] = f2b(wq[d * 512 + n]);
  } else if (i < 65536) {
    int j = i - 32768; int n = j >> 6, d = j & 63;
    wkT[j] = f2b(wk[d * 512 + n]);
  } else if (i < 98304) {
    int j = i - 65536; int n = j >> 6, d = j & 63;
    wvT[j] = f2b(wv[d * 512 + n]);
  } else if (i < 114688) {                           // wdT[e][v] = wd[v][e]
    int j = i - 98304; int e = j >> 8, v = j & 255;
    wdT[j] = f2b(wd[v * 64 + e]);
  } else if (i < 147456) {                           // woT[n][k] = wo[k][n]
    int j = i - 114688; int n = j >> 9, kk = j & 511;
    woT[j] = f2b(wo[kk * 64 + n]);
  } else if (i < 409600) {                           // descb, 4 elems/thread
    int j = (i - 147456) * 4;
    const f32x4 dv = *reinterpret_cast<const f32x4*>(desc + j);
    uint2 pw; pw.x = pk2(dv[0], dv[1]); pw.y = pk2(dv[2], dv[3]);
    *reinterpret_cast<uint2*>(descb + j) = pw;
  }
}

// ---------------------------------------------------------------------------
// Conv3d(P=4,stride=4) + LayerNorm + pos_emb -> vox_emb bf16 [16384][64]
// ---------------------------------------------------------------------------
__global__ __launch_bounds__(256) void k_convln(
    const float* __restrict__ vox, const float* __restrict__ cw,
    const float* __restrict__ cb, const float* __restrict__ lng,
    const float* __restrict__ lnb, const float* __restrict__ pos,
    u16* __restrict__ vox_emb) {
  __shared__ float wT[64 * 65];
  __shared__ float pl[4][64];
  const int t = threadIdx.x;
  for (int i = t; i < 4096; i += 256) wT[(i & 63) * 65 + (i >> 6)] = cw[i];
  const int w = t >> 6, lane = t & 63;
  const float cbl = cb[lane], lg = lng[lane], lb = lnb[lane];
  const int i3 = lane >> 4, j3 = (lane >> 2) & 3, k3 = lane & 3;
  for (int i = 0; i < 8; ++i) {
    const int row = blockIdx.x * 32 + w * 8 + i;
    const int b = row >> 12, np = row & 4095;
    const int pd = np >> 8, ph = (np >> 4) & 15, pw = np & 15;
    __syncthreads();
    pl[w][lane] = vox[(size_t)b * 262144 + (size_t)(pd * 4 + i3) * 4096 +
                      (ph * 4 + j3) * 64 + (pw * 4 + k3)];
    __syncthreads();
    float acc = cbl;
    #pragma unroll
    for (int v = 0; v < 64; ++v) acc += pl[w][v] * wT[v * 65 + lane];
    float s1 = acc, s2 = acc * acc;
    #pragma unroll
    for (int m = 1; m < 64; m <<= 1) { s1 += __shfl_xor(s1, m); s2 += __shfl_xor(s2, m); }
    const float mu = s1 * (1.0f / 64.0f);
    const float var = s2 * (1.0f / 64.0f) - mu * mu;
    const float y = (acc - mu) * rsqrtf(var + 1e-5f) * lg + lb + pos[np * 64 + lane];
    vox_emb[(size_t)row * 64 + lane] = f2b(y);
  }
}

// ---------------------------------------------------------------------------
// des_emb = descb[4096][256] @ wd + bd -> bf16 [4096][64]
// ---------------------------------------------------------------------------
__global__ __launch_bounds__(64) void k_des(
    const u16* __restrict__ descb, const u16* __restrict__ wdT,
    const float* __restrict__ bd, u16* __restrict__ desemb) {
  const int lane = threadIdx.x, lr = lane & 15, lc = lane >> 4;
  const int sd0 = blockIdx.x * 16;
  bf16x8 db[8];
  #pragma unroll
  for (int kc = 0; kc < 8; ++kc)
    db[kc] = asb(ldg16(descb + (size_t)(sd0 + lr) * 256 + kc * 32 + lc * 8));
  #pragma unroll
  for (int et = 0; et < 4; ++et) {
    f32x4 acc = {0.f, 0.f, 0.f, 0.f};
    #pragma unroll
    for (int kc = 0; kc < 8; ++kc) {
      const bf16x8 wa = asb(ldg16(wdT + (size_t)(et * 16 + lr) * 256 + kc * 32 + lc * 8));
      acc = mfma16(wa, db[kc], acc);
    }
    const f32x4 bdv = *reinterpret_cast<const f32x4*>(bd + et * 16 + lc * 4);
    uint2 pw;
    pw.x = pk2(acc[0] + bdv[0], acc[1] + bdv[1]);
    pw.y = pk2(acc[2] + bdv[2], acc[3] + bdv[3]);
    *reinterpret_cast<uint2*>(desemb + (size_t)(sd0 + lr) * 64 + et * 16 + lc * 4) = pw;
  }
}

// ---------------------------------------------------------------------------
// K/V projections, MFMA-fragment-interleaved layouts (proven R6/R7).
// ekl = -|k|^2/2 (f32) — consumed as QK MFMA accumulator init.
// ---------------------------------------------------------------------------
__global__ __launch_bounds__(64) void k_kvproj(
    const u16* __restrict__ desemb, const u16* __restrict__ wkT,
    const float* __restrict__ bk, const u16* __restrict__ wvT,
    const float* __restrict__ bv, u16* __restrict__ kb,
    float* __restrict__ ekl, u16* __restrict__ vtb) {
  const int lane = threadIdx.x, lr = lane & 15, lc = lane >> 4;
  const int x = blockIdx.x, half = blockIdx.y;
  const int b = x >> 6, sd0 = (x & 63) * 16;
  const u16* drow = desemb + (size_t)(x * 16 + lr) * 64;
  const bf16x8 da0 = asb(ldg16(drow + lc * 8));
  const bf16x8 da1 = asb(ldg16(drow + 32 + lc * 8));
  float sq = 0.f;
  #pragma unroll
  for (int et = 0; et < 16; ++et) {                 // K pass (flipped)
    const int etg = half * 16 + et;
    const u16* wrow = wkT + (size_t)(etg * 16 + lr) * 64;
    f32x4 acc = {0.f, 0.f, 0.f, 0.f};
    acc = mfma16(asb(ldg16(wrow + lc * 8)), da0, acc);
    acc = mfma16(asb(ldg16(wrow + 32 + lc * 8)), da1, acc);
    const f32x4 bkv = *reinterpret_cast<const f32x4*>(bk + etg * 16 + lc * 4);
    const float k0 = acc[0] + bkv[0], k1 = acc[1] + bkv[1];
    const float k2 = acc[2] + bkv[2], k3 = acc[3] + bkv[3];
    sq += k0 * k0 + k1 * k1 + k2 * k2 + k3 * k3;
    const int h = etg >> 2, ein = etg & 3;
    const int koff = (ein >> 1) * 32 + lc * 8 + (ein & 1) * 4;
    uint2 pw; pw.x = pk2(k0, k1); pw.y = pk2(k2, k3);
    *reinterpret_cast<uint2*>(kb + ((size_t)(b * 8 + h) * 1024 + sd0 + lr) * 64 + koff) = pw;
    if ((etg & 3) == 3) {
      float s = sq;
      s += __shfl_xor(s, 16); s += __shfl_xor(s, 32);
      if (lc == 0) ekl[(size_t)(b * 8 + h) * 1024 + sd0 + lr] = -0.5f * s;
      sq = 0.f;
    }
  }
  #pragma unroll
  for (int et = 0; et < 16; ++et) {                 // V pass
    const int etg = half * 16 + et;
    const u16* wrow = wvT + (size_t)(etg * 16 + lr) * 64;
    f32x4 acc = {0.f, 0.f, 0.f, 0.f};
    acc = mfma16(da0, asb(ldg16(wrow + lc * 8)), acc);
    acc = mfma16(da1, asb(ldg16(wrow + 32 + lc * 8)), acc);
    const float bvs = bv[etg * 16 + lr];
    const int h = etg >> 2;
    const int voff = ((x & 63) >> 1) * 32 + lc * 8 + (x & 1) * 4;
    uint2 pw;
    pw.x = pk2(acc[0] + bvs, acc[1] + bvs);
    pw.y = pk2(acc[2] + bvs, acc[3] + bvs);
    *reinterpret_cast<uint2*>(vtb + ((size_t)(b * 8 + h) * 64 + (etg & 3) * 16 + lr) * 1024 +
                              voff) = pw;
  }
}

// ---------------------------------------------------------------------------
// Fused Q-projection + L2 attention.
// R8: R5 LDS structure + interleaved b128 fragments + C-init exp chain
// (s = q.k - k^2/2 via MFMA accumulator init) + T14 async staging split
// (load tile t+1 into regs while computing tile t).
// ---------------------------------------------------------------------------
__global__ __launch_bounds__(256, 4) void k_attn(
    const u16* __restrict__ vox_emb, const u16* __restrict__ wqT,
    const float* __restrict__ bq, const float* __restrict__ alpha,
    const u16* __restrict__ kb, const float* __restrict__ eklg,
    const u16* __restrict__ vtb, u16* __restrict__ attn) {
  __shared__ __align__(16) char Kl[128 * 144];   // K tile: 128 rows x 128B, 144B stride
  __shared__ __align__(16) char Vl[64 * 272];    // V tile: 64 e-rows x 256B, 272B stride
  const int t = threadIdx.x, w = t >> 6, lane = t & 63, lr = lane & 15, lc = lane >> 4;
  const int bh = blockIdx.y, b = bh >> 3, h = bh & 7;
  const int q0 = blockIdx.x * 128 + w * 32;   // this wave's 32 q rows

  // ---- Q: q = vox_emb @ wq + bq; fragments hold f2b(q) (unscaled, frozen)
  bf16x8 qf0[2], qf1[2];
  float avL[2];
  {
    bf16x8 vb0[2], vb1[2];
    #pragma unroll
    for (int g = 0; g < 2; ++g) {
      const u16* vrow = vox_emb + (size_t)(b * 4096 + q0 + g * 16 + lr) * 64;
      vb0[g] = asb(ldg16(vrow + lc * 8));
      vb1[g] = asb(ldg16(vrow + 32 + lc * 8));
    }
    float sq[2] = {0.f, 0.f};
    unsigned qd[2][4][2];
    #pragma unroll
    for (int et = 0; et < 4; ++et) {
      const u16* wrow = wqT + (size_t)((h * 4 + et) * 16 + lr) * 64;
      const bf16x8 wa0 = asb(ldg16(wrow + lc * 8));
      const bf16x8 wa1 = asb(ldg16(wrow + 32 + lc * 8));
      const f32x4 bqv = *reinterpret_cast<const f32x4*>(bq + (h * 4 + et) * 16 + lc * 4);
      #pragma unroll
      for (int g = 0; g < 2; ++g) {
        f32x4 acc = {0.f, 0.f, 0.f, 0.f};
        acc = mfma16(wa0, vb0[g], acc);
        acc = mfma16(wa1, vb1[g], acc);
        const float v0 = acc[0] + bqv[0], v1 = acc[1] + bqv[1];
        const float v2 = acc[2] + bqv[2], v3 = acc[3] + bqv[3];
        sq[g] += v0 * v0 + v1 * v1 + v2 * v2 + v3 * v3;
        qd[g][et][0] = pk2(v0, v1);
        qd[g][et][1] = pk2(v2, v3);
      }
    }
    const float ca = L2E * 0.125f * alpha[0];
    #pragma unroll
    for (int g = 0; g < 2; ++g) {
      float s = sq[g];
      s += __shfl_xor(s, 16); s += __shfl_xor(s, 32);
      avL[g] = ca * __expf(-s);     // log2e * alpha*SCALE*exp(-|q|^2)
      qf0[g] = mk8(qd[g][0][0], qd[g][0][1], qd[g][1][0], qd[g][1][1]);
      qf1[g] = mk8(qd[g][2][0], qd[g][2][1], qd[g][3][0], qd[g][3][1]);
    }
  }

  const f32x4 z = {0.f, 0.f, 0.f, 0.f};
  f32x4 o[2][4];
  float dn[2] = {0.f, 0.f};
  #pragma unroll
  for (int g = 0; g < 2; ++g)
    #pragma unroll
    for (int m = 0; m < 4; ++m) o[g][m] = z;

  // staging thread mapping: K 128 rows x 128B (thread = half row);
  // V 64 rows x 256B (thread = quarter row). Both coalesced 64B/lane.
  const int rk = t >> 1, hk = (t & 1) * 4;
  const int re = t >> 2, hv = (t & 3) * 4;
  const V4* ksrc = reinterpret_cast<const V4*>(kb) + (size_t)bh * 8192 +
                   (size_t)rk * 8 + hk;
  const char* vsrc = reinterpret_cast<const char*>(vtb) + (size_t)bh * 131072 +
                     (size_t)re * 2048 + hv * 16;
  V4* kdst = reinterpret_cast<V4*>(Kl + rk * 144 + hk * 16);
  V4* vdst = reinterpret_cast<V4*>(Vl + re * 272 + hv * 16);
  const float* ekh = eklg + (size_t)bh * 1024;

  // preload tile 0 into regs
  V4 sk0 = ksrc[0], sk1 = ksrc[1], sk2 = ksrc[2], sk3 = ksrc[3];
  V4 sv0 = *reinterpret_cast<const V4*>(vsrc);
  V4 sv1 = *reinterpret_cast<const V4*>(vsrc + 16);
  V4 sv2 = *reinterpret_cast<const V4*>(vsrc + 32);
  V4 sv3 = *reinterpret_cast<const V4*>(vsrc + 48);

  const float C2 = 2.8853900817779268f;   // 2*log2(e)

  for (int kt = 0; kt < 8; ++kt) {
    // write staged regs -> LDS
    kdst[0] = sk0; kdst[1] = sk1; kdst[2] = sk2; kdst[3] = sk3;
    vdst[0] = sv0; vdst[1] = sv1; vdst[2] = sv2; vdst[3] = sv3;
    __syncthreads();
    // issue next tile's loads (hidden under compute)
    if (kt < 7) {
      const V4* ks = ksrc + (size_t)(kt + 1) * 1024;
      const char* vs = vsrc + (size_t)(kt + 1) * 256;
      sk0 = ks[0]; sk1 = ks[1]; sk2 = ks[2]; sk3 = ks[3];
      sv0 = *reinterpret_cast<const V4*>(vs);
      sv1 = *reinterpret_cast<const V4*>(vs + 16);
      sv2 = *reinterpret_cast<const V4*>(vs + 32);
      sv3 = *reinterpret_cast<const V4*>(vs + 48);
    }
    #pragma unroll
    for (int c2 = 0; c2 < 4; ++c2) {
      const int kk = kt * 4 + c2;
      const char* kr0 = Kl + (c2 * 32 + lr) * 144 + lc * 16;
      const char* kr1 = kr0 + 16 * 144;
      const bf16x8 ka00 = asb(*reinterpret_cast<const V4*>(kr0));
      const bf16x8 ka01 = asb(*reinterpret_cast<const V4*>(kr0 + 64));
      const bf16x8 ka10 = asb(*reinterpret_cast<const V4*>(kr1));
      const bf16x8 ka11 = asb(*reinterpret_cast<const V4*>(kr1 + 64));
      const char* vrb = Vl + lr * 272 + c2 * 64 + lc * 16;
      const bf16x8 va0 = asb(*reinterpret_cast<const V4*>(vrb));
      const bf16x8 va1 = asb(*reinterpret_cast<const V4*>(vrb + 16 * 272));
      const bf16x8 va2 = asb(*reinterpret_cast<const V4*>(vrb + 32 * 272));
      const bf16x8 va3 = asb(*reinterpret_cast<const V4*>(vrb + 48 * 272));
      const f32x4 ce0 = *reinterpret_cast<const f32x4*>(ekh + kk * 32 + lc * 4);
      const f32x4 ce1 = *reinterpret_cast<const f32x4*>(ekh + kk * 32 + 16 + lc * 4);
      #pragma unroll
      for (int g = 0; g < 2; ++g) {
        f32x4 s0 = ce0, s1 = ce1;   // C-init = -|k|^2/2
        s0 = mfma16(ka00, qf0[g], s0); s0 = mfma16(ka01, qf1[g], s0);
        s1 = mfma16(ka10, qf0[g], s1); s1 = mfma16(ka11, qf1[g], s1);
        // t = exp(2qk - k^2) = 2^(C2*s);  p = exp(av*t) = 2^(avL*t)
        const float t00 = EXP2(C2 * s0[0]), t01 = EXP2(C2 * s0[1]);
        const float t02 = EXP2(C2 * s0[2]), t03 = EXP2(C2 * s0[3]);
        const float t10 = EXP2(C2 * s1[0]), t11 = EXP2(C2 * s1[1]);
        const float t12 = EXP2(C2 * s1[2]), t13 = EXP2(C2 * s1[3]);
        const float p00 = EXP2(avL[g] * t00), p01 = EXP2(avL[g] * t01);
        const float p02 = EXP2(avL[g] * t02), p03 = EXP2(avL[g] * t03);
        const float p10 = EXP2(avL[g] * t10), p11 = EXP2(avL[g] * t11);
        const float p12 = EXP2(avL[g] * t12), p13 = EXP2(avL[g] * t13);
        dn[g] += ((p00 + p01) + (p02 + p03)) + ((p10 + p11) + (p12 + p13));
        const bf16x8 pf = mk8(pkbf(p00, p01), pkbf(p02, p03),
                              pkbf(p10, p11), pkbf(p12, p13));
        o[g][0] = mfma16(va0, pf, o[g][0]);
        o[g][1] = mfma16(va1, pf, o[g][1]);
        o[g][2] = mfma16(va2, pf, o[g][2]);
        o[g][3] = mfma16(va3, pf, o[g][3]);
      }
    }
    __syncthreads();
  }

  u16* obase = attn + (size_t)(b * 4096 + q0 + lr) * 512 + h * 64 + lc * 4;
  #pragma unroll
  for (int g = 0; g < 2; ++g) {
    float s = dn[g];
    s += __shfl_xor(s, 16); s += __shfl_xor(s, 32);   // sum lane's k-subsets over lc
    const float inv = 1.0f / s;
    #pragma unroll
    for (int m = 0; m < 4; ++m) {
      uint2 pw;
      pw.x = pk2(o[g][m][0] * inv, o[g][m][1] * inv);
      pw.y = pk2(o[g][m][2] * inv, o[g][m][3] * inv);
      *reinterpret_cast<uint2*>(obase + (size_t)g * 16 * 512 + m * 16) = pw;
    }
  }
}

// ---------------------------------------------------------------------------
// out = attn[16384][512] @ wo + bo -> fp32 [16384][64]
// ---------------------------------------------------------------------------
__global__ __launch_bounds__(64) void k_out(
    const u16* __restrict__ attn, const u16* __restrict__ woT,
    const float* __restrict__ bo, float* __restrict__ out) {
  const int lane = threadIdx.x, lr = lane & 15, lc = lane >> 4;
  const int np0 = blockIdx.x * 16;
  const u16* arow = attn + (size_t)(np0 + lr) * 512;
  f32x4 acc[4] = {{0.f,0.f,0.f,0.f},{0.f,0.f,0.f,0.f},{0.f,0.f,0.f,0.f},{0.f,0.f,0.f,0.f}};
  #pragma unroll
  for (int kc = 0; kc < 16; ++kc) {
    const bf16x8 bfr = asb(ldg16(arow + kc * 32 + lc * 8));
    #pragma unroll
    for (int et = 0; et < 4; ++et) {
      const bf16x8 wa = asb(ldg16(woT + (size_t)(et * 16 + lr) * 512 + kc * 32 + lc * 8));
      acc[et] = mfma16(wa, bfr, acc[et]);
    }
  }
  #pragma unroll
  for (int et = 0; et < 4; ++et) {
    const f32x4 bov = *reinterpret_cast<const f32x4*>(bo + et * 16 + lc * 4);
    const f32x4 r = acc[et] + bov;
    *reinterpret_cast<f32x4*>(out + (size_t)(np0 + lr) * 64 + et * 16 + lc * 4) = r;
  }
}

// ---------------------------------------------------------------------------
extern "C" void kernel_launch(void* const* d_in, const int* in_sizes, int n_in,
                              void* d_out, int out_size, void* d_ws, size_t ws_size,
                              hipStream_t stream) {
  (void)in_sizes; (void)n_in; (void)out_size; (void)ws_size;
  const float* vox   = (const float*)d_in[0];
  const float* desc  = (const float*)d_in[1];
  const float* cw    = (const float*)d_in[2];
  const float* cb    = (const float*)d_in[3];
  const float* lng   = (const float*)d_in[4];
  const float* lnb   = (const float*)d_in[5];
  const float* pos   = (const float*)d_in[6];
  const float* wq    = (const float*)d_in[7];
  const float* bq    = (const float*)d_in[8];
  const float* wk    = (const float*)d_in[9];
  const float* bk    = (const float*)d_in[10];
  const float* wv    = (const float*)d_in[11];
  const float* bv    = (const float*)d_in[12];
  const float* wd    = (const float*)d_in[13];
  const float* bd    = (const float*)d_in[14];
  const float* alpha = (const float*)d_in[15];
  const float* wo    = (const float*)d_in[16];
  const float* bo    = (const float*)d_in[17];
  float* out = (float*)d_out;

  char* ws = (char*)d_ws;
  size_t off = 0;
  auto alloc = [&](size_t bytes) {
    char* p = ws + off;
    off += (bytes + 255) & ~(size_t)255;
    return p;
  };
  u16*   vox_emb = (u16*)alloc((size_t)16384 * 64 * 2);
  u16*   descb   = (u16*)alloc((size_t)4096 * 256 * 2);
  u16*   desemb  = (u16*)alloc((size_t)4096 * 64 * 2);
  u16*   kb      = (u16*)alloc((size_t)4096 * 512 * 2);
  u16*   vtb     = (u16*)alloc((size_t)4096 * 512 * 2);
  float* ekl     = (float*)alloc((size_t)32768 * 4);
  u16*   attn    = (u16*)alloc((size_t)16384 * 512 * 2);
  u16*   wqT     = (u16*)alloc((size_t)32768 * 2);
  u16*   wkT     = (u16*)alloc((size_t)32768 * 2);
  u16*   wvT     = (u16*)alloc((size_t)32768 * 2);
  u16*   wdT     = (u16*)alloc((size_t)16384 * 2);
  u16*   woT     = (u16*)alloc((size_t)32768 * 2);

  k_prep<<<1600, 256, 0, stream>>>(wq, wk, wv, wd, wo, desc, wqT, wkT, wvT, wdT, woT, descb);
  k_convln<<<512, 256, 0, stream>>>(vox, cw, cb, lng, lnb, pos, vox_emb);
  k_des<<<256, 64, 0, stream>>>(descb, wdT, bd, desemb);
  k_kvproj<<<dim3(256, 2), 64, 0, stream>>>(desemb, wkT, bk, wvT, bv, kb, ekl, vtb);
  k_attn<<<dim3(32, 32), 256, 0, stream>>>(vox_emb, wqT, bq, alpha, kb, ekl, vtb, attn);
  k_out<<<1024, 64, 0, stream>>>(attn, woT, bo, out);
}

// Round 9
// 116.595 us; speedup vs baseline: 1.9912x; 1.6497x over previous
//
#include <hip/hip_runtime.h>

typedef unsigned short u16;
typedef __bf16 bf16x8 __attribute__((ext_vector_type(8)));
typedef float f32x4 __attribute__((ext_vector_type(4)));

struct alignas(16) V4 { unsigned x, y, z, w; };

#if __has_builtin(__builtin_amdgcn_exp2f)
#define EXP2(x) __builtin_amdgcn_exp2f(x)
#else
#define EXP2(x) __expf((x) * 0.6931471805599453f)
#endif
#define L2E 1.4426950408889634f

// f32 -> bf16 RTNE (bit-twiddle; HW-verified R1/R4)
__device__ __forceinline__ u16 f2b(float f) {
  unsigned u = __builtin_bit_cast(unsigned, f);
  u += 0x7FFFu + ((u >> 16) & 1u);
  return (u16)(u >> 16);
}
// RTNE pack of two f32 -> u32 (lo = a, hi = b)
__device__ __forceinline__ unsigned pk2(float a, float b) {
  return (unsigned)f2b(a) | ((unsigned)f2b(b) << 16);
}
// HW packed cvt: used ONLY for P fragment (validated R8: absmax unchanged)
__device__ __forceinline__ unsigned pkbf(float a, float b) {
  unsigned d;
  asm("v_cvt_pk_bf16_f32 %0, %1, %2" : "=v"(d) : "v"(a), "v"(b));
  return d;
}
__device__ __forceinline__ bf16x8 asb(V4 v) { return __builtin_bit_cast(bf16x8, v); }
__device__ __forceinline__ bf16x8 mk8(unsigned a, unsigned b, unsigned c, unsigned d) {
  V4 v; v.x = a; v.y = b; v.z = c; v.w = d; return asb(v);
}
__device__ __forceinline__ V4 ldg16(const u16* p) { return *reinterpret_cast<const V4*>(p); }
__device__ __forceinline__ f32x4 mfma16(bf16x8 a, bf16x8 b, f32x4 c) {
  return __builtin_amdgcn_mfma_f32_16x16x32_bf16(a, b, c, 0, 0, 0);
}
// Direct global->LDS DMA, 16B/lane, LDS dest = wave-uniform base + lane*16.
__device__ __forceinline__ void gload_lds16(const void* g, void* l) {
  __builtin_amdgcn_global_load_lds(
      (const __attribute__((address_space(1))) int*)g,
      (__attribute__((address_space(3))) int*)l, 16, 0, 0);
}

// ---------------------------------------------------------------------------
// Prep: transpose+cast weights to bf16, cast descriptor to bf16.
// ---------------------------------------------------------------------------
__global__ __launch_bounds__(256) void k_prep(
    const float* __restrict__ wq, const float* __restrict__ wk,
    const float* __restrict__ wv, const float* __restrict__ wd,
    const float* __restrict__ wo, const float* __restrict__ desc,
    u16* __restrict__ wqT, u16* __restrict__ wkT, u16* __restrict__ wvT,
    u16* __restrict__ wdT, u16* __restrict__ woT, u16* __restrict__ descb) {
  int i = blockIdx.x * 256 + threadIdx.x;
  if (i < 32768) {                                   // wqT[n][d] = wq[d][n]
    int n = i >> 6, d = i & 63;
    wqT[i] = f2b(wq[d * 512 + n]);
  } else if (i < 65536) {
    int j = i - 32768; int n = j >> 6, d = j & 63;
    wkT[j] = f2b(wk[d * 512 + n]);
  } else if (i < 98304) {
    int j = i - 65536; int n = j >> 6, d = j & 63;
    wvT[j] = f2b(wv[d * 512 + n]);
  } else if (i < 114688) {                           // wdT[e][v] = wd[v][e]
    int j = i - 98304; int e = j >> 8, v = j & 255;
    wdT[j] = f2b(wd[v * 64 + e]);
  } else if (i < 147456) {                           // woT[n][k] = wo[k][n]
    int j = i - 114688; int n = j >> 9, kk = j & 511;
    woT[j] = f2b(wo[kk * 64 + n]);
  } else if (i < 409600) {                           // descb, 4 elems/thread
    int j = (i - 147456) * 4;
    const f32x4 dv = *reinterpret_cast<const f32x4*>(desc + j);
    uint2 pw; pw.x = pk2(dv[0], dv[1]); pw.y = pk2(dv[2], dv[3]);
    *reinterpret_cast<uint2*>(descb + j) = pw;
  }
}

// ---------------------------------------------------------------------------
// Conv3d(P=4,stride=4) + LayerNorm + pos_emb -> vox_emb bf16 [16384][64]
// ---------------------------------------------------------------------------
__global__ __launch_bounds__(256) void k_convln(
    const float* __restrict__ vox, const float* __restrict__ cw,
    const float* __restrict__ cb, const float* __restrict__ lng,
    const float* __restrict__ lnb, const float* __restrict__ pos,
    u16* __restrict__ vox_emb) {
  __shared__ float wT[64 * 65];
  __shared__ float pl[4][64];
  const int t = threadIdx.x;
  for (int i = t; i < 4096; i += 256) wT[(i & 63) * 65 + (i >> 6)] = cw[i];
  const int w = t >> 6, lane = t & 63;
  const float cbl = cb[lane], lg = lng[lane], lb = lnb[lane];
  const int i3 = lane >> 4, j3 = (lane >> 2) & 3, k3 = lane & 3;
  for (int i = 0; i < 8; ++i) {
    const int row = blockIdx.x * 32 + w * 8 + i;
    const int b = row >> 12, np = row & 4095;
    const int pd = np >> 8, ph = (np >> 4) & 15, pw = np & 15;
    __syncthreads();
    pl[w][lane] = vox[(size_t)b * 262144 + (size_t)(pd * 4 + i3) * 4096 +
                      (ph * 4 + j3) * 64 + (pw * 4 + k3)];
    __syncthreads();
    float acc = cbl;
    #pragma unroll
    for (int v = 0; v < 64; ++v) acc += pl[w][v] * wT[v * 65 + lane];
    float s1 = acc, s2 = acc * acc;
    #pragma unroll
    for (int m = 1; m < 64; m <<= 1) { s1 += __shfl_xor(s1, m); s2 += __shfl_xor(s2, m); }
    const float mu = s1 * (1.0f / 64.0f);
    const float var = s2 * (1.0f / 64.0f) - mu * mu;
    const float y = (acc - mu) * rsqrtf(var + 1e-5f) * lg + lb + pos[np * 64 + lane];
    vox_emb[(size_t)row * 64 + lane] = f2b(y);
  }
}

// ---------------------------------------------------------------------------
// des_emb = descb[4096][256] @ wd + bd -> bf16 [4096][64]
// ---------------------------------------------------------------------------
__global__ __launch_bounds__(64) void k_des(
    const u16* __restrict__ descb, const u16* __restrict__ wdT,
    const float* __restrict__ bd, u16* __restrict__ desemb) {
  const int lane = threadIdx.x, lr = lane & 15, lc = lane >> 4;
  const int sd0 = blockIdx.x * 16;
  bf16x8 db[8];
  #pragma unroll
  for (int kc = 0; kc < 8; ++kc)
    db[kc] = asb(ldg16(descb + (size_t)(sd0 + lr) * 256 + kc * 32 + lc * 8));
  #pragma unroll
  for (int et = 0; et < 4; ++et) {
    f32x4 acc = {0.f, 0.f, 0.f, 0.f};
    #pragma unroll
    for (int kc = 0; kc < 8; ++kc) {
      const bf16x8 wa = asb(ldg16(wdT + (size_t)(et * 16 + lr) * 256 + kc * 32 + lc * 8));
      acc = mfma16(wa, db[kc], acc);
    }
    const f32x4 bdv = *reinterpret_cast<const f32x4*>(bd + et * 16 + lc * 4);
    uint2 pw;
    pw.x = pk2(acc[0] + bdv[0], acc[1] + bdv[1]);
    pw.y = pk2(acc[2] + bdv[2], acc[3] + bdv[3]);
    *reinterpret_cast<uint2*>(desemb + (size_t)(sd0 + lr) * 64 + et * 16 + lc * 4) = pw;
  }
}

// ---------------------------------------------------------------------------
// K/V projections. kb/vtb stored as per-(bh,kt) 16KB LDS tile IMAGES with
// XOR swizzle (col16 ^= row&7) baked in, so k_attn can stage with linear
// global_load_lds and read ds_read_b128 conflict-free.
//   K tile: 128 rows(sd) x 128B; V tile: 64 rows(e) x 256B.
// ekl = -|k|^2/2 (f32) — consumed as QK MFMA accumulator init (validated R8).
// ---------------------------------------------------------------------------
__global__ __launch_bounds__(64) void k_kvproj(
    const u16* __restrict__ desemb, const u16* __restrict__ wkT,
    const float* __restrict__ bk, const u16* __restrict__ wvT,
    const float* __restrict__ bv, u16* __restrict__ kb,
    float* __restrict__ ekl, u16* __restrict__ vtb) {
  const int lane = threadIdx.x, lr = lane & 15, lc = lane >> 4;
  const int x = blockIdx.x, half = blockIdx.y;
  const int b = x >> 6, sb = x & 63, sd0 = sb * 16;
  char* kbc = reinterpret_cast<char*>(kb);
  char* vtc = reinterpret_cast<char*>(vtb);
  const u16* drow = desemb + (size_t)(x * 16 + lr) * 64;
  const bf16x8 da0 = asb(ldg16(drow + lc * 8));
  const bf16x8 da1 = asb(ldg16(drow + 32 + lc * 8));
  // K-pass row mapping (per lane): sd = sd0+lr
  const int sd = sd0 + lr, ktK = sd >> 7, rK = sd & 127, xrK = rK & 7;
  float sq = 0.f;
  #pragma unroll
  for (int et = 0; et < 16; ++et) {                 // K pass (flipped)
    const int etg = half * 16 + et;
    const u16* wrow = wkT + (size_t)(etg * 16 + lr) * 64;
    f32x4 acc = {0.f, 0.f, 0.f, 0.f};
    acc = mfma16(asb(ldg16(wrow + lc * 8)), da0, acc);
    acc = mfma16(asb(ldg16(wrow + 32 + lc * 8)), da1, acc);
    const f32x4 bkv = *reinterpret_cast<const f32x4*>(bk + etg * 16 + lc * 4);
    const float k0 = acc[0] + bkv[0], k1 = acc[1] + bkv[1];
    const float k2 = acc[2] + bkv[2], k3 = acc[3] + bkv[3];
    sq += k0 * k0 + k1 * k1 + k2 * k2 + k3 * k3;
    const int h = etg >> 2, ein = etg & 3;
    const int col16s = (((ein >> 1) * 4 + lc) ^ xrK);
    uint2 pw; pw.x = pk2(k0, k1); pw.y = pk2(k2, k3);
    *reinterpret_cast<uint2*>(kbc + (size_t)(b * 8 + h) * 131072 + ktK * 16384 +
                              rK * 128 + col16s * 16 + (ein & 1) * 8) = pw;
    if ((etg & 3) == 3) {
      float s = sq;
      s += __shfl_xor(s, 16); s += __shfl_xor(s, 32);
      if (lc == 0) ekl[(size_t)(b * 8 + h) * 1024 + sd0 + lr] = -0.5f * s;
      sq = 0.f;
    }
  }
  // V-pass column mapping (per block): tile = sb>>3, kk_local = (sb>>1)&3
  const int ktV = sb >> 3, kkl = (sb >> 1) & 3, half8 = sb & 1;
  #pragma unroll
  for (int et = 0; et < 16; ++et) {                 // V pass
    const int etg = half * 16 + et;
    const u16* wrow = wvT + (size_t)(etg * 16 + lr) * 64;
    f32x4 acc = {0.f, 0.f, 0.f, 0.f};
    acc = mfma16(da0, asb(ldg16(wrow + lc * 8)), acc);
    acc = mfma16(da1, asb(ldg16(wrow + 32 + lc * 8)), acc);
    const float bvs = bv[etg * 16 + lr];
    const int h = etg >> 2;
    const int e = (etg & 3) * 16 + lr;
    const int col16s = ((kkl * 4 + lc) ^ (e & 7));
    uint2 pw;
    pw.x = pk2(acc[0] + bvs, acc[1] + bvs);
    pw.y = pk2(acc[2] + bvs, acc[3] + bvs);
    *reinterpret_cast<uint2*>(vtc + (size_t)(b * 8 + h) * 131072 + ktV * 16384 +
                              e * 256 + col16s * 16 + half8 * 8) = pw;
  }
}

// ---------------------------------------------------------------------------
// Fused Q-projection + L2 attention. R8-validated arithmetic (frozen).
// R9: staging via global_load_lds (zero VGPR, 8 inst/wave/tile) into linear
// 16KB tile images; ds_read_b128 with XOR-swizzled columns (conflict-free).
// ---------------------------------------------------------------------------
__global__ __launch_bounds__(256, 4) void k_attn(
    const u16* __restrict__ vox_emb, const u16* __restrict__ wqT,
    const float* __restrict__ bq, const float* __restrict__ alpha,
    const u16* __restrict__ kb, const float* __restrict__ eklg,
    const u16* __restrict__ vtb, u16* __restrict__ attn) {
  __shared__ __align__(16) char Kl[16384];   // K tile: 128 rows x 128B, linear
  __shared__ __align__(16) char Vl[16384];   // V tile: 64 rows x 256B, linear
  const int t = threadIdx.x, w = t >> 6, lane = t & 63, lr = lane & 15, lc = lane >> 4;
  const int bh = blockIdx.y, b = bh >> 3, h = bh & 7;
  const int q0 = blockIdx.x * 128 + w * 32;   // this wave's 32 q rows

  // ---- Q: q = vox_emb @ wq + bq; fragments hold f2b(q) (unscaled, frozen)
  bf16x8 qf0[2], qf1[2];
  float avL[2];
  {
    bf16x8 vb0[2], vb1[2];
    #pragma unroll
    for (int g = 0; g < 2; ++g) {
      const u16* vrow = vox_emb + (size_t)(b * 4096 + q0 + g * 16 + lr) * 64;
      vb0[g] = asb(ldg16(vrow + lc * 8));
      vb1[g] = asb(ldg16(vrow + 32 + lc * 8));
    }
    float sq[2] = {0.f, 0.f};
    unsigned qd[2][4][2];
    #pragma unroll
    for (int et = 0; et < 4; ++et) {
      const u16* wrow = wqT + (size_t)((h * 4 + et) * 16 + lr) * 64;
      const bf16x8 wa0 = asb(ldg16(wrow + lc * 8));
      const bf16x8 wa1 = asb(ldg16(wrow + 32 + lc * 8));
      const f32x4 bqv = *reinterpret_cast<const f32x4*>(bq + (h * 4 + et) * 16 + lc * 4);
      #pragma unroll
      for (int g = 0; g < 2; ++g) {
        f32x4 acc = {0.f, 0.f, 0.f, 0.f};
        acc = mfma16(wa0, vb0[g], acc);
        acc = mfma16(wa1, vb1[g], acc);
        const float v0 = acc[0] + bqv[0], v1 = acc[1] + bqv[1];
        const float v2 = acc[2] + bqv[2], v3 = acc[3] + bqv[3];
        sq[g] += v0 * v0 + v1 * v1 + v2 * v2 + v3 * v3;
        qd[g][et][0] = pk2(v0, v1);
        qd[g][et][1] = pk2(v2, v3);
      }
    }
    const float ca = L2E * 0.125f * alpha[0];
    #pragma unroll
    for (int g = 0; g < 2; ++g) {
      float s = sq[g];
      s += __shfl_xor(s, 16); s += __shfl_xor(s, 32);
      avL[g] = ca * __expf(-s);     // log2e * alpha*SCALE*exp(-|q|^2)
      qf0[g] = mk8(qd[g][0][0], qd[g][0][1], qd[g][1][0], qd[g][1][1]);
      qf1[g] = mk8(qd[g][2][0], qd[g][2][1], qd[g][3][0], qd[g][3][1]);
    }
  }

  const f32x4 z = {0.f, 0.f, 0.f, 0.f};
  f32x4 o[2][4];
  float dn[2] = {0.f, 0.f};
  #pragma unroll
  for (int g = 0; g < 2; ++g)
    #pragma unroll
    for (int m = 0; m < 4; ++m) o[g][m] = z;

  const char* kimg = reinterpret_cast<const char*>(kb) + (size_t)bh * 131072;
  const char* vimg = reinterpret_cast<const char*>(vtb) + (size_t)bh * 131072;
  const float* ekh = eklg + (size_t)bh * 1024;
  const int xr = lr & 7;                       // XOR swizzle key
  const float C2 = 2.8853900817779268f;        // 2*log2(e)

  for (int kt = 0; kt < 8; ++kt) {
    {  // stage 32KB via global_load_lds: each wave DMAs its 4KB of K and V
      const char* kg = kimg + kt * 16384 + w * 4096 + lane * 16;
      const char* vg = vimg + kt * 16384 + w * 4096 + lane * 16;
      char* kl = Kl + w * 4096;
      char* vl = Vl + w * 4096;
      gload_lds16(kg,        kl);
      gload_lds16(kg + 1024, kl + 1024);
      gload_lds16(kg + 2048, kl + 2048);
      gload_lds16(kg + 3072, kl + 3072);
      gload_lds16(vg,        vl);
      gload_lds16(vg + 1024, vl + 1024);
      gload_lds16(vg + 2048, vl + 2048);
      gload_lds16(vg + 3072, vl + 3072);
    }
    __syncthreads();   // drains vmcnt (loads landed) + all waves
    #pragma unroll
    for (int c2 = 0; c2 < 4; ++c2) {
      const int kk = kt * 4 + c2;
      const char* kr0 = Kl + (c2 * 32 + lr) * 128;
      const char* kr1 = kr0 + 16 * 128;
      const bf16x8 ka00 = asb(*reinterpret_cast<const V4*>(kr0 + ((lc ^ xr) << 4)));
      const bf16x8 ka01 = asb(*reinterpret_cast<const V4*>(kr0 + (((lc + 4) ^ xr) << 4)));
      const bf16x8 ka10 = asb(*reinterpret_cast<const V4*>(kr1 + ((lc ^ xr) << 4)));
      const bf16x8 ka11 = asb(*reinterpret_cast<const V4*>(kr1 + (((lc + 4) ^ xr) << 4)));
      const int vcol = ((c2 * 4 + lc) ^ xr) << 4;
      const char* vrb = Vl + lr * 256 + vcol;
      const bf16x8 va0 = asb(*reinterpret_cast<const V4*>(vrb));
      const bf16x8 va1 = asb(*reinterpret_cast<const V4*>(vrb + 16 * 256));
      const bf16x8 va2 = asb(*reinterpret_cast<const V4*>(vrb + 32 * 256));
      const bf16x8 va3 = asb(*reinterpret_cast<const V4*>(vrb + 48 * 256));
      const f32x4 ce0 = *reinterpret_cast<const f32x4*>(ekh + kk * 32 + lc * 4);
      const f32x4 ce1 = *reinterpret_cast<const f32x4*>(ekh + kk * 32 + 16 + lc * 4);
      #pragma unroll
      for (int g = 0; g < 2; ++g) {
        f32x4 s0 = ce0, s1 = ce1;   // C-init = -|k|^2/2
        s0 = mfma16(ka00, qf0[g], s0); s0 = mfma16(ka01, qf1[g], s0);
        s1 = mfma16(ka10, qf0[g], s1); s1 = mfma16(ka11, qf1[g], s1);
        // t = exp(2qk - k^2) = 2^(C2*s);  p = exp(av*t) = 2^(avL*t)
        const float t00 = EXP2(C2 * s0[0]), t01 = EXP2(C2 * s0[1]);
        const float t02 = EXP2(C2 * s0[2]), t03 = EXP2(C2 * s0[3]);
        const float t10 = EXP2(C2 * s1[0]), t11 = EXP2(C2 * s1[1]);
        const float t12 = EXP2(C2 * s1[2]), t13 = EXP2(C2 * s1[3]);
        const float p00 = EXP2(avL[g] * t00), p01 = EXP2(avL[g] * t01);
        const float p02 = EXP2(avL[g] * t02), p03 = EXP2(avL[g] * t03);
        const float p10 = EXP2(avL[g] * t10), p11 = EXP2(avL[g] * t11);
        const float p12 = EXP2(avL[g] * t12), p13 = EXP2(avL[g] * t13);
        dn[g] += ((p00 + p01) + (p02 + p03)) + ((p10 + p11) + (p12 + p13));
        const bf16x8 pf = mk8(pkbf(p00, p01), pkbf(p02, p03),
                              pkbf(p10, p11), pkbf(p12, p13));
        o[g][0] = mfma16(va0, pf, o[g][0]);
        o[g][1] = mfma16(va1, pf, o[g][1]);
        o[g][2] = mfma16(va2, pf, o[g][2]);
        o[g][3] = mfma16(va3, pf, o[g][3]);
      }
    }
    __syncthreads();   // protect LDS before next tile's DMA
  }

  u16* obase = attn + (size_t)(b * 4096 + q0 + lr) * 512 + h * 64 + lc * 4;
  #pragma unroll
  for (int g = 0; g < 2; ++g) {
    float s = dn[g];
    s += __shfl_xor(s, 16); s += __shfl_xor(s, 32);   // sum lane's k-subsets over lc
    const float inv = 1.0f / s;
    #pragma unroll
    for (int m = 0; m < 4; ++m) {
      uint2 pw;
      pw.x = pk2(o[g][m][0] * inv, o[g][m][1] * inv);
      pw.y = pk2(o[g][m][2] * inv, o[g][m][3] * inv);
      *reinterpret_cast<uint2*>(obase + (size_t)g * 16 * 512 + m * 16) = pw;
    }
  }
}

// ---------------------------------------------------------------------------
// out = attn[16384][512] @ wo + bo -> fp32 [16384][64]
// ---------------------------------------------------------------------------
__global__ __launch_bounds__(64) void k_out(
    const u16* __restrict__ attn, const u16* __restrict__ woT,
    const float* __restrict__ bo, float* __restrict__ out) {
  const int lane = threadIdx.x, lr = lane & 15, lc = lane >> 4;
  const int np0 = blockIdx.x * 16;
  const u16* arow = attn + (size_t)(np0 + lr) * 512;
  f32x4 acc[4] = {{0.f,0.f,0.f,0.f},{0.f,0.f,0.f,0.f},{0.f,0.f,0.f,0.f},{0.f,0.f,0.f,0.f}};
  #pragma unroll
  for (int kc = 0; kc < 16; ++kc) {
    const bf16x8 bfr = asb(ldg16(arow + kc * 32 + lc * 8));
    #pragma unroll
    for (int et = 0; et < 4; ++et) {
      const bf16x8 wa = asb(ldg16(woT + (size_t)(et * 16 + lr) * 512 + kc * 32 + lc * 8));
      acc[et] = mfma16(wa, bfr, acc[et]);
    }
  }
  #pragma unroll
  for (int et = 0; et < 4; ++et) {
    const f32x4 bov = *reinterpret_cast<const f32x4*>(bo + et * 16 + lc * 4);
    const f32x4 r = acc[et] + bov;
    *reinterpret_cast<f32x4*>(out + (size_t)(np0 + lr) * 64 + et * 16 + lc * 4) = r;
  }
}

// ---------------------------------------------------------------------------
extern "C" void kernel_launch(void* const* d_in, const int* in_sizes, int n_in,
                              void* d_out, int out_size, void* d_ws, size_t ws_size,
                              hipStream_t stream) {
  (void)in_sizes; (void)n_in; (void)out_size; (void)ws_size;
  const float* vox   = (const float*)d_in[0];
  const float* desc  = (const float*)d_in[1];
  const float* cw    = (const float*)d_in[2];
  const float* cb    = (const float*)d_in[3];
  const float* lng   = (const float*)d_in[4];
  const float* lnb   = (const float*)d_in[5];
  const float* pos   = (const float*)d_in[6];
  const float* wq    = (const float*)d_in[7];
  const float* bq    = (const float*)d_in[8];
  const float* wk    = (const float*)d_in[9];
  const float* bk    = (const float*)d_in[10];
  const float* wv    = (const float*)d_in[11];
  const float* bv    = (const float*)d_in[12];
  const float* wd    = (const float*)d_in[13];
  const float* bd    = (const float*)d_in[14];
  const float* alpha = (const float*)d_in[15];
  const float* wo    = (const float*)d_in[16];
  const float* bo    = (const float*)d_in[17];
  float* out = (float*)d_out;

  char* ws = (char*)d_ws;
  size_t off = 0;
  auto alloc = [&](size_t bytes) {
    char* p = ws + off;
    off += (bytes + 255) & ~(size_t)255;
    return p;
  };
  u16*   vox_emb = (u16*)alloc((size_t)16384 * 64 * 2);
  u16*   descb   = (u16*)alloc((size_t)4096 * 256 * 2);
  u16*   desemb  = (u16*)alloc((size_t)4096 * 64 * 2);
  u16*   kb      = (u16*)alloc((size_t)4096 * 512 * 2);
  u16*   vtb     = (u16*)alloc((size_t)4096 * 512 * 2);
  float* ekl     = (float*)alloc((size_t)32768 * 4);
  u16*   attn    = (u16*)alloc((size_t)16384 * 512 * 2);
  u16*   wqT     = (u16*)alloc((size_t)32768 * 2);
  u16*   wkT     = (u16*)alloc((size_t)32768 * 2);
  u16*   wvT     = (u16*)alloc((size_t)32768 * 2);
  u16*   wdT     = (u16*)alloc((size_t)16384 * 2);
  u16*   woT     = (u16*)alloc((size_t)32768 * 2);

  k_prep<<<1600, 256, 0, stream>>>(wq, wk, wv, wd, wo, desc, wqT, wkT, wvT, wdT, woT, descb);
  k_convln<<<512, 256, 0, stream>>>(vox, cw, cb, lng, lnb, pos, vox_emb);
  k_des<<<256, 64, 0, stream>>>(descb, wdT, bd, desemb);
  k_kvproj<<<dim3(256, 2), 64, 0, stream>>>(desemb, wkT, bk, wvT, bv, kb, ekl, vtb);
  k_attn<<<dim3(32, 32), 256, 0, stream>>>(vox_emb, wqT, bq, alpha, kb, ekl, vtb, attn);
  k_out<<<1024, 64, 0, stream>>>(attn, woT, bo, out);
}